// Round 11
// baseline (140.644 us; speedup 1.0000x reference)
//
#include <hip/hip_runtime.h>
#include <float.h>

#define K_CODES 1024
#define DIM 64
#define T_LEN 8192
#define N_TOK 131072          // 16 * 8192 tokens
#define LO_SCALE 2048.0f

typedef _Float16 half8  __attribute__((ext_vector_type(8)));   // 4 VGPRs: MFMA A/B frag
typedef float    f32x16 __attribute__((ext_vector_type(16)));  // 32x32 MFMA C/D frag

#define MFMA32(a, b, c) __builtin_amdgcn_mfma_f32_32x32x16_f16((a), (b), (c), 0, 0, 0)

// ---------------- prep: codebook -> 32-code tiles, B-side-scaled f16 split ----------------
// Tile ct (32 codes) = 8 KB: [set(hs,ls)][kc 0..3][lane 0..63][j 0..7], where the B frag
// for k-chunk kc is B[n = lane&31][k = kc*16 + (lane>>5)*8 + j].
// hs = 2048*f16(e) (exact exponent shift), ls = 2048*(e - f16(e)).  wesq = 2048*||e||^2.
__global__ void vq_prep(const float* __restrict__ cb,
                        _Float16* __restrict__ w,
                        float* __restrict__ wesq) {
    __shared__ float part[256];
    const int ct   = blockIdx.x;        // 32 tiles of 32 codes
    const int t    = threadIdx.x;
    const int kc   = t >> 6;
    const int lane = t & 63;
    const int n    = lane & 31;
    const int kh   = lane >> 5;

    const float* src = cb + (size_t)(ct * 32 + n) * DIM + kc * 16 + kh * 8;
    float4 v0 = *reinterpret_cast<const float4*>(src);
    float4 v1 = *reinterpret_cast<const float4*>(src + 4);
    float x[8] = {v0.x, v0.y, v0.z, v0.w, v1.x, v1.y, v1.z, v1.w};

    half8 hs, ls;
    float psum = 0.0f;
    #pragma unroll
    for (int j = 0; j < 8; ++j) {
        _Float16 bh = (_Float16)x[j];
        hs[j] = (_Float16)((float)bh * LO_SCALE);             // exact (exponent shift)
        ls[j] = (_Float16)((x[j] - (float)bh) * LO_SCALE);    // (e - bh) exact in fp32
        psum = fmaf(x[j], x[j], psum);
    }
    _Float16* wt = w + (size_t)ct * 4096;
    *reinterpret_cast<half8*>(wt + 0 * 2048 + kc * 512 + lane * 8) = hs;
    *reinterpret_cast<half8*>(wt + 1 * 2048 + kc * 512 + lane * 8) = ls;

    part[t] = psum;
    __syncthreads();
    if (t < 32) {   // t = code n; sum the 8 (kc,kh) partials: indices g*32 + n
        float s = 0.0f;
        #pragma unroll
        for (int g = 0; g < 8; ++g) s += part[g * 32 + t];
        wesq[ct * 32 + t] = s * LO_SCALE;
    }
}

// ---------------- main: 32x32x16 MFMA, global-direct B, single-acc scaled score ----------------
// r6-r10: duration tracks the MFMA floor with ~3x dilation regardless of B-path/
// occupancy/ILP shape. So shrink the floor: 32x32x16 (4060 vs 3378 FLOP/cyc/CU,
// floor 24.8 -> 20.7 us, half the MFMA instruction count) and B-side 2048 scaling
// (A needs only {ah, al} sets). Score' = ah*bh_s + ah*bl_s + al*bh_s — bit-identical
// products to r10 => identical argmins.
__global__ __launch_bounds__(256, 2)
void vq_main(const float* __restrict__ in,
             const float* __restrict__ cb,
             const _Float16* __restrict__ w,
             const float* __restrict__ wesq,
             float* __restrict__ out) {
    __shared__ float esq_s[K_CODES];   // 4 KB (scaled x2048)
    __shared__ int   idx_s[256];

    const int tid  = threadIdx.x;
    const int wave = tid >> 6;
    const int lane = tid & 63;
    const int n5   = lane & 31;   // code col in C; token row in A
    const int kh   = lane >> 5;   // k-half selector in A/B frags; row-group bit in C

    for (int k = tid; k < K_CODES; k += 256) esq_s[k] = wesq[k];
    __syncthreads();   // only barrier before the epilogue

    const int strip = blockIdx.x * 256 + wave * 64;   // 64 tokens per wave (2 m-tiles of 32)
    const int b  = strip >> 13;
    const int t0 = strip & 8191;

    // ---- A fragments: -2x -> ah = f16(x), al = f16(x - ah); frag k = kc*16 + kh*8 + j ----
    const float* xin = in + (size_t)b * DIM * T_LEN + t0;
    half8 a_h[2][4], a_l[2][4];
    #pragma unroll
    for (int mt = 0; mt < 2; ++mt) {
        #pragma unroll
        for (int kc = 0; kc < 4; ++kc) {
            half8 hh, ll;
            #pragma unroll
            for (int j = 0; j < 8; ++j) {
                const int d = kc * 16 + kh * 8 + j;
                float xv = -2.0f * xin[(size_t)d * T_LEN + mt * 32 + n5];
                _Float16 ah = (_Float16)xv;
                hh[j] = ah;
                ll[j] = (_Float16)(xv - (float)ah);   // exact residual, f16-rounded
            }
            a_h[mt][kc] = hh;
            a_l[mt][kc] = ll;
        }
    }

    float best[32];
    int   bidx[32];
    #pragma unroll
    for (int i = 0; i < 32; ++i) { best[i] = FLT_MAX; bidx[i] = 0; }

    const _Float16* wb = w + (size_t)lane * 8;

    half8 Ah[4], Al[4], Bh[4], Bl[4];
    float Ae, Be;
    auto loadB = [&](int ct, half8* h, half8* l, float& es) {
        const _Float16* p = wb + (size_t)ct * 4096;
        #pragma unroll
        for (int kc = 0; kc < 4; ++kc) {
            h[kc] = *reinterpret_cast<const half8*>(p + kc * 512);          // hs (x2048)
            l[kc] = *reinterpret_cast<const half8*>(p + 2048 + kc * 512);   // ls (x2048)
        }
        es = esq_s[ct * 32 + n5];
    };
    auto step = [&](const half8* h, const half8* l, float es, int ct) {
        const int code = ct * 32 + n5;
        #pragma unroll
        for (int mt = 0; mt < 2; ++mt) {
            f32x16 c;
            #pragma unroll
            for (int r = 0; r < 16; ++r) c[r] = es;   // 2048*||e||^2 folded into C
            #pragma unroll
            for (int kc = 0; kc < 4; ++kc) c = MFMA32(a_h[mt][kc], h[kc], c);  // 2048 ah bh
            #pragma unroll
            for (int kc = 0; kc < 4; ++kc) c = MFMA32(a_h[mt][kc], l[kc], c);  // ah * 2048 bl
            #pragma unroll
            for (int kc = 0; kc < 4; ++kc) c = MFMA32(a_l[mt][kc], h[kc], c);  // al * 2048 bh
            #pragma unroll
            for (int r = 0; r < 16; ++r) {
                float sc = c[r];
                const int i = mt * 16 + r;
                bool lt = sc < best[i];   // strict <: first occurrence wins
                best[i] = lt ? sc : best[i];
                bidx[i] = lt ? code : bidx[i];
            }
        }
    };

    // ping-pong: tile ct+1's 8 global loads in flight during tile ct's 24 MFMAs
    loadB(0, Ah, Al, Ae);
    loadB(1, Bh, Bl, Be);
    for (int p = 0; p < 15; ++p) {
        step(Ah, Al, Ae, 2 * p);
        loadB(2 * p + 2, Ah, Al, Ae);
        step(Bh, Bl, Be, 2 * p + 1);
        loadB(2 * p + 3, Bh, Bl, Be);
    }
    step(Ah, Al, Ae, 30);
    step(Bh, Bl, Be, 31);

    // ---- cross-lane merge over the 32 code lanes (xor low 5 bits; kh preserved) ----
    #pragma unroll
    for (int i = 0; i < 32; ++i) {
        float s = best[i];
        int  ix = bidx[i];
        #pragma unroll
        for (int off = 1; off < 32; off <<= 1) {
            float s2 = __shfl_xor(s, off, 64);
            int  ix2 = __shfl_xor(ix, off, 64);
            bool take = (s2 < s) || (s2 == s && ix2 < ix);  // tie -> lower index
            s  = take ? s2 : s;
            ix = take ? ix2 : ix;
        }
        if (n5 == 0) {
            // C row = (r&3) + 8*(r>>2) + 4*kh; token_local = mt*32 + row
            const int mt = i >> 4, r = i & 15;
            const int row = (r & 3) + 8 * (r >> 2) + 4 * kh;
            idx_s[wave * 64 + mt * 32 + row] = ix;
        }
    }
    __syncthreads();

    // ---- epilogue: 1 thread per token, gather exact fp32 row + coalesced stores ----
    const int token = blockIdx.x * 256 + tid;
    const int tb = token >> 13;
    const int tt = token & 8191;
    const int my_idx = idx_s[tid];

    out[(size_t)N_TOK * DIM + token] = (float)my_idx;   // index output

    const float* crow = cb + (size_t)my_idx * DIM;
    float* outv = out + (size_t)tb * DIM * T_LEN + tt;
    #pragma unroll
    for (int d0 = 0; d0 < DIM; d0 += 4) {
        float4 v = *reinterpret_cast<const float4*>(crow + d0);  // L2-hot gather
        outv[(size_t)(d0 + 0) * T_LEN] = v.x;
        outv[(size_t)(d0 + 1) * T_LEN] = v.y;
        outv[(size_t)(d0 + 2) * T_LEN] = v.z;
        outv[(size_t)(d0 + 3) * T_LEN] = v.w;
    }
}

extern "C" void kernel_launch(void* const* d_in, const int* in_sizes, int n_in,
                              void* d_out, int out_size, void* d_ws, size_t ws_size,
                              hipStream_t stream) {
    const float* in = (const float*)d_in[0];   // (16, 64, 8192) fp32
    const float* cb = (const float*)d_in[1];   // (1024, 64) fp32
    float* out = (float*)d_out;

    _Float16* w   = (_Float16*)d_ws;                       // 32 tiles * 8 KB = 256 KB
    float*   wesq = (float*)((char*)d_ws + 32 * 8192);     // 4 KB

    vq_prep<<<dim3(32), dim3(256), 0, stream>>>(cb, w, wesq);
    vq_main<<<dim3(N_TOK / 256), dim3(256), 0, stream>>>(in, cb, w, wesq, out);
}